// Round 5
// baseline (215.051 us; speedup 1.0000x reference)
//
#include <hip/hip_runtime.h>

#define NG 8000
#define V1 2562
#define V2 10242
#define V3 40962
#define E1 7680
#define E2 30720
#define E3 122880
#define NPRED (V1 + V2 + V3)   /* 53766 */
#define ND1   (3 * NG)         /* 24000 */
#define ABATCH 8
#define MAXCHUNK 512

struct PassTab {
    int NA[6], NB[6], h[6], xb[6], ny[6], chunk[6], poff[6], base[7];
};

__device__ __forceinline__ double block_reduce_add(double v, double* sm) {
    int lane = threadIdx.x & 63;
    int wid  = threadIdx.x >> 6;
    for (int off = 32; off > 0; off >>= 1) v += __shfl_down(v, off, 64);
    if (lane == 0) sm[wid] = v;
    __syncthreads();
    double r = 0.0;
    if (wid == 0) {
        int nw = blockDim.x >> 6;
        r = (lane < nw) ? sm[lane] : 0.0;
        for (int off = 32; off > 0; off >>= 1) r += __shfl_down(r, off, 64);
    }
    return r;  /* valid on thread 0 */
}

/* All six chamfer passes in ONE launch. Block bid -> (pass, xblk, yblk).
   Each block stages its B-chunk into LDS (norms computed on the fly),
   each thread owns 8 A points (t + q*h). Tracks m = min_j (Bn - 2*A.B);
   result max(An + m, 0) written to a PRIVATE partial slot [yblk][t'] --
   no atomics, no init kernel (every slot written unconditionally). */
__launch_bounds__(256)
__global__ void k_pair_all(const float* __restrict__ gt,
                           const float* __restrict__ q1,
                           const float* __restrict__ q2,
                           const float* __restrict__ q3,
                           float* __restrict__ partial,
                           double* __restrict__ acc, PassTab T) {
    __shared__ float4 sb[MAXCHUNK];
    int bid = blockIdx.x, tid = threadIdx.x;
    if (bid == 0 && tid < 8) acc[tid] = 0.0;   /* zero acc for k_post */

    int p = 0;
    while (p < 5 && bid >= T.base[p + 1]) ++p;  /* uniform, 6 passes */
    int rel  = bid - T.base[p];
    int xb   = T.xb[p];
    int xblk = rel % xb, yblk = rel / xb;
    int NA = T.NA[p], NB = T.NB[p], h = T.h[p], chunk = T.chunk[p];
    int pi = (p < 3) ? p : p - 3;
    const float* pr = (pi == 0) ? q1 : ((pi == 1) ? q2 : q3);
    const float* A  = (p < 3) ? gt : pr;
    const float* B  = (p < 3) ? pr : gt;

    int j0 = yblk * chunk;
    int cnt = min(NB - j0, chunk);
    for (int i = tid; i < cnt; i += 256) {
        int j = 3 * (j0 + i);
        float x = B[j], y = B[j + 1], z = B[j + 2];
        sb[i] = make_float4(x, y, z, fmaf(x, x, fmaf(y, y, z * z)));
    }
    __syncthreads();

    int t = xblk * 256 + tid;
    if (t >= h) return;

    float nx[ABATCH], ny_[ABATCH], nz[ABATCH], aw[ABATCH], m[ABATCH];
#pragma unroll
    for (int q = 0; q < ABATCH; ++q) {
        int tq = t + q * h; if (tq > NA - 1) tq = NA - 1;
        int j = 3 * tq;
        float x = A[j], y = A[j + 1], z = A[j + 2];
        nx[q] = -2.f * x; ny_[q] = -2.f * y; nz[q] = -2.f * z;
        aw[q] = fmaf(x, x, fmaf(y, y, z * z));
        m[q] = __builtin_inff();
    }

#define DOT(q, bb) fmaf(nz[q], bb.z, fmaf(ny_[q], bb.y, fmaf(nx[q], bb.x, bb.w)))
    int k = 0;
    for (; k + 4 <= cnt; k += 4) {
        float4 b0 = sb[k], b1 = sb[k + 1], b2 = sb[k + 2], b3 = sb[k + 3];
#pragma unroll
        for (int q = 0; q < ABATCH; ++q) {
            float d0 = DOT(q, b0), d1 = DOT(q, b1);
            float d2 = DOT(q, b2), d3 = DOT(q, b3);
            m[q] = fminf(fminf(m[q], d0), d1);   /* -> v_min3_f32 */
            m[q] = fminf(fminf(m[q], d2), d3);
        }
    }
    for (; k < cnt; ++k) {
        float4 b = sb[k];
#pragma unroll
        for (int q = 0; q < ABATCH; ++q) m[q] = fminf(m[q], DOT(q, b));
    }
#undef DOT

    float* pp = partial + T.poff[p] + yblk * NA;
#pragma unroll
    for (int q = 0; q < ABATCH; ++q) {
        int tq = t + q * h;
        if (tq < NA) pp[tq] = fmaxf(aw[q] + m[q], 0.f);
    }
}

/* partial-min fold + chamfer means + edge + laplace, one kernel. */
#define R0 (ND1 + NPRED)
#define R1 (E1 + E2 + E3)
#define R2 NPRED
__global__ void k_post(const float* __restrict__ partial,
                       const float* __restrict__ p1, const float* __restrict__ p2,
                       const float* __restrict__ p3,
                       const int* __restrict__ e1, const int* __restrict__ e2,
                       const int* __restrict__ e3,
                       const float* __restrict__ f1, const float* __restrict__ f2,
                       const float* __restrict__ f3,
                       const int* __restrict__ l1, const int* __restrict__ l2,
                       const int* __restrict__ l3,
                       double* __restrict__ acc, PassTab T) {
    __shared__ double sm[8];
    double s0 = 0.0, s1 = 0.0, s2 = 0.0;
    int stride = gridDim.x * blockDim.x;
    int gid = blockIdx.x * blockDim.x + threadIdx.x;
    for (int i = gid; i < R0 + R1 + R2; i += stride) {
        if (i < R0) {
            int p, t; double w;
            if (i < ND1) { p = i / NG; t = i - p * NG; w = 1.0 / NG; }
            else {
                int q = i - ND1;
                if (q < V1)            { p = 3; t = q;            w = 1.0 / V1; }
                else if (q < V1 + V2)  { p = 4; t = q - V1;       w = 1.0 / V2; }
                else                   { p = 5; t = q - V1 - V2;  w = 1.0 / V3; }
            }
            const float* src = partial + T.poff[p] + t;
            int NA = T.NA[p], ny = T.ny[p];
            float mn = __builtin_inff();
            for (int c = 0; c < ny; ++c) mn = fminf(mn, src[c * NA]);
            s0 += (double)mn * w;
        } else if (i < R0 + R1) {
            int q = i - R0;
            const float* p; const int* e; int k; double w;
            if (q < E1)            { p = p1; e = e1; k = q;            w = 1.0 / E1; }
            else if (q < E1 + E2)  { p = p2; e = e2; k = q - E1;       w = 1.0 / E2; }
            else                   { p = p3; e = e3; k = q - E1 - E2;  w = 1.0 / E3; }
            int u = e[2 * k], v = e[2 * k + 1];
            float dx = p[3 * u]     - p[3 * v];
            float dy = p[3 * u + 1] - p[3 * v + 1];
            float dz = p[3 * u + 2] - p[3 * v + 2];
            s1 += w * (double)(dx * dx + dy * dy + dz * dz);
        } else {
            int q = i - R0 - R1;
            const float* f; const float* p; const int* l; int k; double w;
            if (q < V1)            { f = f1; p = p1; l = l1; k = q;            w = 0.2 / V1; }
            else if (q < V1 + V2)  { f = f2; p = p2; l = l2; k = q - V1;       w = 1.0 / V2; }
            else                   { f = f3; p = p3; l = l3; k = q - V1 - V2;  w = 1.0 / V3; }
            const int* row = l + 10 * k;
            float sfx = 0.f, sfy = 0.f, sfz = 0.f, spx = 0.f, spy = 0.f, spz = 0.f;
#pragma unroll
            for (int r = 0; r < 8; ++r) {
                int n = row[r];
                if (n >= 0) {
                    sfx += f[3 * n]; sfy += f[3 * n + 1]; sfz += f[3 * n + 2];
                    spx += p[3 * n]; spy += p[3 * n + 1]; spz += p[3 * n + 2];
                }
            }
            float inv = 1.0f / (float)row[9];
            float dx = (f[3 * k]     - p[3 * k])     - (sfx - spx) * inv;
            float dy = (f[3 * k + 1] - p[3 * k + 1]) - (sfy - spy) * inv;
            float dz = (f[3 * k + 2] - p[3 * k + 2]) - (sfz - spz) * inv;
            s2 += w * (double)(dx * dx + dy * dy + dz * dz);
        }
    }
    double r0 = block_reduce_add(s0, sm); __syncthreads();
    double r1 = block_reduce_add(s1, sm); __syncthreads();
    double r2 = block_reduce_add(s2, sm);
    if (threadIdx.x == 0) {
        atomicAdd(acc + 0, r0);
        atomicAdd(acc + 1, r1);
        atomicAdd(acc + 2, r2);
    }
}

__global__ void k_final(const double* __restrict__ acc, float* __restrict__ out) {
    if (threadIdx.x == 0 && blockIdx.x == 0) {
        double ch = acc[0], ed = acc[1], lp = acc[2];
        out[0] = (float)(100.0 * ch + 0.1 * ed + 0.3 * lp);
        out[1] = (float)ch;
        out[2] = (float)ed;
        out[3] = (float)lp;
    }
}

static void build_tab(PassTab& T, int* partialFloats) {
    const int NAs[6] = { NG, NG, NG, V1, V2, V3 };
    const int NBs[6] = { V1, V2, V3, NG, NG, NG };
    const long target = 400000;   /* pairs per block */
    int poff = 0, base = 0;
    for (int p = 0; p < 6; ++p) {
        int NA = NAs[p], NB = NBs[p];
        int h  = (NA + ABATCH - 1) / ABATCH;
        int xb = (h + 255) / 256;
        long pairs = (long)NA * NB;
        int blocks = (int)((pairs + target - 1) / target);
        if (blocks < xb) blocks = xb;
        int ny = blocks / xb; if (ny < 1) ny = 1;
        int chunk = (NB + ny - 1) / ny;
        if (chunk > MAXCHUNK) chunk = MAXCHUNK;
        ny = (NB + chunk - 1) / chunk;   /* all chunks nonempty */
        T.NA[p] = NA; T.NB[p] = NB; T.h[p] = h; T.xb[p] = xb;
        T.ny[p] = ny; T.chunk[p] = chunk; T.poff[p] = poff; T.base[p] = base;
        poff += ny * NA;
        base += xb * ny;
    }
    T.base[6] = base;
    *partialFloats = poff;
}

extern "C" void kernel_launch(void* const* d_in, const int* in_sizes, int n_in,
                              void* d_out, int out_size, void* d_ws, size_t ws_size,
                              hipStream_t stream) {
    const float *pp[3], *pf[3], *gt;
    const int *ed[3], *li[3];
    if (in_sizes[1] == 3 * V1) {
        /* setup_inputs() dict order: (pts,feats,edges,lap)*3, gt */
        pp[0] = (const float*)d_in[0];  pf[0] = (const float*)d_in[1];
        ed[0] = (const int*)d_in[2];    li[0] = (const int*)d_in[3];
        pp[1] = (const float*)d_in[4];  pf[1] = (const float*)d_in[5];
        ed[1] = (const int*)d_in[6];    li[1] = (const int*)d_in[7];
        pp[2] = (const float*)d_in[8];  pf[2] = (const float*)d_in[9];
        ed[2] = (const int*)d_in[10];   li[2] = (const int*)d_in[11];
        gt = (const float*)d_in[12];
    } else {
        /* reference signature order */
        pp[0] = (const float*)d_in[0];  pp[1] = (const float*)d_in[1];  pp[2] = (const float*)d_in[2];
        pf[0] = (const float*)d_in[3];  pf[1] = (const float*)d_in[4];  pf[2] = (const float*)d_in[5];
        gt    = (const float*)d_in[6];
        ed[0] = (const int*)d_in[7];    ed[1] = (const int*)d_in[8];    ed[2] = (const int*)d_in[9];
        li[0] = (const int*)d_in[10];   li[1] = (const int*)d_in[11];   li[2] = (const int*)d_in[12];
    }

    PassTab T; int pFloats;
    build_tab(T, &pFloats);

    char* ws = (char*)d_ws;
    double* acc     = (double*)ws;        /* 8 doubles          */
    float*  partial = (float*)(ws + 64);  /* ~4.2M floats       */

    k_pair_all<<<T.base[6], 256, 0, stream>>>(gt, pp[0], pp[1], pp[2],
                                              partial, acc, T);
    k_post<<<256, 256, 0, stream>>>(partial, pp[0], pp[1], pp[2],
                                    ed[0], ed[1], ed[2],
                                    pf[0], pf[1], pf[2],
                                    li[0], li[1], li[2], acc, T);
    k_final<<<1, 64, 0, stream>>>(acc, (float*)d_out);
}

// Round 6
// 171.013 us; speedup vs baseline: 1.2575x; 1.2575x over previous
//
#include <hip/hip_runtime.h>

#define NG 8000
#define V1 2562
#define V2 10242
#define V3 40962
#define E1 7680
#define E2 30720
#define E3 122880
#define NPRED (V1 + V2 + V3)   /* 53766 */
#define ND1   (3 * NG)         /* 24000 */
#define NMIN  (ND1 + NPRED)    /* 77766 */
#define ABATCH 16
#define MAXCHUNK 512

struct PassTab {
    int NA[6], NB[6], h[6], xb[6], chunk[6], ooff[6], base[7];
};

__device__ __forceinline__ double block_reduce_add(double v, double* sm) {
    int lane = threadIdx.x & 63;
    int wid  = threadIdx.x >> 6;
    for (int off = 32; off > 0; off >>= 1) v += __shfl_down(v, off, 64);
    if (lane == 0) sm[wid] = v;
    __syncthreads();
    double r = 0.0;
    if (wid == 0) {
        int nw = blockDim.x >> 6;
        r = (lane < nw) ? sm[lane] : 0.0;
        for (int off = 32; off > 0; off >>= 1) r += __shfl_down(r, off, 64);
    }
    return r;  /* valid on thread 0 */
}

__global__ void k_init(unsigned int* __restrict__ mins, double* __restrict__ acc) {
    int i = blockIdx.x * blockDim.x + threadIdx.x;
    if (i < 8) acc[i] = 0.0;
    int stride = gridDim.x * blockDim.x;
    for (int k = i; k < NMIN; k += stride) mins[k] = 0x7f800000u; /* +inf */
}

/* All six chamfer passes, ONE launch, atomicMin outputs (no fold pass —
   r5 lesson: partial-array fold cost ~2x the atomics it replaced).
   Block -> (pass, xblk, yblk); block stages its B-chunk (norms on the
   fly) into LDS; thread owns 16 A points (t + q*h); inner loop reads
   LDS at wave-uniform addresses (broadcast). reads/pair = 1/(64*ABATCH)
   keeps the LDS pipe well under the VALU pipe. Tracks
   m = min_j (Bn - 2*A.B); result max(An + m, 0) >= 0 so float-as-uint
   atomicMin ordering is valid. */
__launch_bounds__(256)
__global__ void k_pair_all(const float* __restrict__ gt,
                           const float* __restrict__ q1,
                           const float* __restrict__ q2,
                           const float* __restrict__ q3,
                           unsigned int* __restrict__ mins, PassTab T) {
    __shared__ float4 sb[MAXCHUNK];
    int bid = blockIdx.x, tid = threadIdx.x;

    int p = 0;
    while (p < 5 && bid >= T.base[p + 1]) ++p;  /* wave-uniform */
    int rel  = bid - T.base[p];
    int xb   = T.xb[p];
    int xblk = rel % xb, yblk = rel / xb;
    int NA = T.NA[p], NB = T.NB[p], h = T.h[p], chunk = T.chunk[p];
    int pi = (p < 3) ? p : p - 3;
    const float* pr = (pi == 0) ? q1 : ((pi == 1) ? q2 : q3);
    const float* A  = (p < 3) ? gt : pr;
    const float* B  = (p < 3) ? pr : gt;

    int j0 = yblk * chunk;
    int cnt = min(NB - j0, chunk);
    for (int i = tid; i < cnt; i += 256) {
        int j = 3 * (j0 + i);
        float x = B[j], y = B[j + 1], z = B[j + 2];
        sb[i] = make_float4(x, y, z, fmaf(x, x, fmaf(y, y, z * z)));
    }
    __syncthreads();

    int t = xblk * 256 + tid;
    if (t >= h) return;

    float nx[ABATCH], ny_[ABATCH], nz[ABATCH], aw[ABATCH], m[ABATCH];
#pragma unroll
    for (int q = 0; q < ABATCH; ++q) {
        int tq = t + q * h; if (tq > NA - 1) tq = NA - 1;
        int j = 3 * tq;
        float x = A[j], y = A[j + 1], z = A[j + 2];
        nx[q] = -2.f * x; ny_[q] = -2.f * y; nz[q] = -2.f * z;
        aw[q] = fmaf(x, x, fmaf(y, y, z * z));
        m[q] = __builtin_inff();
    }

#define DOT(q, bb) fmaf(nz[q], bb.z, fmaf(ny_[q], bb.y, fmaf(nx[q], bb.x, bb.w)))
    int k = 0;
    for (; k + 2 <= cnt; k += 2) {
        float4 b0 = sb[k], b1 = sb[k + 1];
#pragma unroll
        for (int q = 0; q < ABATCH; ++q) {
            float d0 = DOT(q, b0), d1 = DOT(q, b1);
            m[q] = fminf(fminf(m[q], d0), d1);   /* -> v_min3_f32 */
        }
    }
    if (k < cnt) {
        float4 b = sb[k];
#pragma unroll
        for (int q = 0; q < ABATCH; ++q) m[q] = fminf(m[q], DOT(q, b));
    }
#undef DOT

    unsigned int* out = mins + T.ooff[p];
#pragma unroll
    for (int q = 0; q < ABATCH; ++q) {
        int tq = t + q * h;
        if (tq < NA) atomicMin(out + tq, __float_as_uint(fmaxf(aw[q] + m[q], 0.f)));
    }
}

/* chamfer means + edge + laplace, one kernel (r4-proven structure). */
#define R0 NMIN
#define R1 (E1 + E2 + E3)
#define R2 NPRED
__global__ void k_post(const unsigned int* __restrict__ mins,
                       const float* __restrict__ p1, const float* __restrict__ p2,
                       const float* __restrict__ p3,
                       const int* __restrict__ e1, const int* __restrict__ e2,
                       const int* __restrict__ e3,
                       const float* __restrict__ f1, const float* __restrict__ f2,
                       const float* __restrict__ f3,
                       const int* __restrict__ l1, const int* __restrict__ l2,
                       const int* __restrict__ l3,
                       double* __restrict__ acc) {
    __shared__ double sm[8];
    double s0 = 0.0, s1 = 0.0, s2 = 0.0;
    int stride = gridDim.x * blockDim.x;
    int gid = blockIdx.x * blockDim.x + threadIdx.x;
    for (int i = gid; i < R0 + R1 + R2; i += stride) {
        if (i < R0) {
            double w;
            if (i < ND1) w = 1.0 / NG;
            else {
                int t = i - ND1;
                w = (t < V1) ? (1.0 / V1) : ((t < V1 + V2) ? (1.0 / V2) : (1.0 / V3));
            }
            s0 += (double)__uint_as_float(mins[i]) * w;
        } else if (i < R0 + R1) {
            int q = i - R0;
            const float* p; const int* e; int k; double w;
            if (q < E1)            { p = p1; e = e1; k = q;            w = 1.0 / E1; }
            else if (q < E1 + E2)  { p = p2; e = e2; k = q - E1;       w = 1.0 / E2; }
            else                   { p = p3; e = e3; k = q - E1 - E2;  w = 1.0 / E3; }
            int u = e[2 * k], v = e[2 * k + 1];
            float dx = p[3 * u]     - p[3 * v];
            float dy = p[3 * u + 1] - p[3 * v + 1];
            float dz = p[3 * u + 2] - p[3 * v + 2];
            s1 += w * (double)(dx * dx + dy * dy + dz * dz);
        } else {
            int q = i - R0 - R1;
            const float* f; const float* p; const int* l; int k; double w;
            if (q < V1)            { f = f1; p = p1; l = l1; k = q;            w = 0.2 / V1; }
            else if (q < V1 + V2)  { f = f2; p = p2; l = l2; k = q - V1;       w = 1.0 / V2; }
            else                   { f = f3; p = p3; l = l3; k = q - V1 - V2;  w = 1.0 / V3; }
            const int* row = l + 10 * k;
            float sfx = 0.f, sfy = 0.f, sfz = 0.f, spx = 0.f, spy = 0.f, spz = 0.f;
#pragma unroll
            for (int r = 0; r < 8; ++r) {
                int n = row[r];
                if (n >= 0) {
                    sfx += f[3 * n]; sfy += f[3 * n + 1]; sfz += f[3 * n + 2];
                    spx += p[3 * n]; spy += p[3 * n + 1]; spz += p[3 * n + 2];
                }
            }
            float inv = 1.0f / (float)row[9];
            float dx = (f[3 * k]     - p[3 * k])     - (sfx - spx) * inv;
            float dy = (f[3 * k + 1] - p[3 * k + 1]) - (sfy - spy) * inv;
            float dz = (f[3 * k + 2] - p[3 * k + 2]) - (sfz - spz) * inv;
            s2 += w * (double)(dx * dx + dy * dy + dz * dz);
        }
    }
    double r0 = block_reduce_add(s0, sm); __syncthreads();
    double r1 = block_reduce_add(s1, sm); __syncthreads();
    double r2 = block_reduce_add(s2, sm);
    if (threadIdx.x == 0) {
        atomicAdd(acc + 0, r0);
        atomicAdd(acc + 1, r1);
        atomicAdd(acc + 2, r2);
    }
}

__global__ void k_final(const double* __restrict__ acc, float* __restrict__ out) {
    if (threadIdx.x == 0 && blockIdx.x == 0) {
        double ch = acc[0], ed = acc[1], lp = acc[2];
        out[0] = (float)(100.0 * ch + 0.1 * ed + 0.3 * lp);
        out[1] = (float)ch;
        out[2] = (float)ed;
        out[3] = (float)lp;
    }
}

static void build_tab(PassTab& T) {
    const int NAs[6]  = { NG, NG, NG, V1, V2, V3 };
    const int NBs[6]  = { V1, V2, V3, NG, NG, NG };
    const int ooff[6] = { 0, NG, 2 * NG, ND1, ND1 + V1, ND1 + V1 + V2 };
    const double totalPairs = 2.0 * ((double)NG * NPRED);
    const int TARGET_BLOCKS = 1024;
    int base = 0;
    for (int p = 0; p < 6; ++p) {
        int NA = NAs[p], NB = NBs[p];
        int h  = (NA + ABATCH - 1) / ABATCH;
        int xb = (h + 255) / 256;
        double share = ((double)NA * NB) / totalPairs;
        int ny = (int)(share * TARGET_BLOCKS / xb + 0.5);
        int nyMin = (NB + MAXCHUNK - 1) / MAXCHUNK;   /* chunk <= 512 */
        int nyMax = NB / 128;                         /* chunk >= 128 */
        if (nyMax < nyMin) nyMax = nyMin;
        if (ny < nyMin) ny = nyMin;
        if (ny > nyMax) ny = nyMax;
        int chunk = (NB + ny - 1) / ny;
        ny = (NB + chunk - 1) / chunk;                /* all chunks nonempty */
        T.NA[p] = NA; T.NB[p] = NB; T.h[p] = h; T.xb[p] = xb;
        T.chunk[p] = chunk; T.ooff[p] = ooff[p]; T.base[p] = base;
        base += xb * ny;
    }
    T.base[6] = base;
}

extern "C" void kernel_launch(void* const* d_in, const int* in_sizes, int n_in,
                              void* d_out, int out_size, void* d_ws, size_t ws_size,
                              hipStream_t stream) {
    const float *pp[3], *pf[3], *gt;
    const int *ed[3], *li[3];
    if (in_sizes[1] == 3 * V1) {
        /* setup_inputs() dict order: (pts,feats,edges,lap)*3, gt */
        pp[0] = (const float*)d_in[0];  pf[0] = (const float*)d_in[1];
        ed[0] = (const int*)d_in[2];    li[0] = (const int*)d_in[3];
        pp[1] = (const float*)d_in[4];  pf[1] = (const float*)d_in[5];
        ed[1] = (const int*)d_in[6];    li[1] = (const int*)d_in[7];
        pp[2] = (const float*)d_in[8];  pf[2] = (const float*)d_in[9];
        ed[2] = (const int*)d_in[10];   li[2] = (const int*)d_in[11];
        gt = (const float*)d_in[12];
    } else {
        /* reference signature order */
        pp[0] = (const float*)d_in[0];  pp[1] = (const float*)d_in[1];  pp[2] = (const float*)d_in[2];
        pf[0] = (const float*)d_in[3];  pf[1] = (const float*)d_in[4];  pf[2] = (const float*)d_in[5];
        gt    = (const float*)d_in[6];
        ed[0] = (const int*)d_in[7];    ed[1] = (const int*)d_in[8];    ed[2] = (const int*)d_in[9];
        li[0] = (const int*)d_in[10];   li[1] = (const int*)d_in[11];   li[2] = (const int*)d_in[12];
    }

    PassTab T;
    build_tab(T);

    char* ws = (char*)d_ws;
    double*       acc  = (double*)ws;              /* 8 doubles      */
    unsigned int* mins = (unsigned int*)(ws + 64); /* NMIN uints     */

    k_init<<<160, 256, 0, stream>>>(mins, acc);
    k_pair_all<<<T.base[6], 256, 0, stream>>>(gt, pp[0], pp[1], pp[2], mins, T);
    k_post<<<256, 256, 0, stream>>>(mins, pp[0], pp[1], pp[2],
                                    ed[0], ed[1], ed[2],
                                    pf[0], pf[1], pf[2],
                                    li[0], li[1], li[2], acc);
    k_final<<<1, 64, 0, stream>>>(acc, (float*)d_out);
}